// Round 1
// 198.901 us; speedup vs baseline: 1.0324x; 1.0324x over previous
//
#include <hip/hip_runtime.h>
#include <math.h>

#define V 100000
#define D 256
#define B 32
#define N 128
#define K 100
#define NPOS (B * N)             // 4096
#define NPAIR (NPOS * (K + 1))   // 413,696 = 1616 * 256 exactly
#define BIN_ROWS 32
#define NBIN (V / BIN_ROWS)      // 3125
#define NSHARD 16
#define CAP_S 32                 // pairs per (bin,shard); mean 8.3, +8 sigma
#define MAXTOT (NSHARD * CAP_S)  // 512
#define GRIDC 1024               // persistent compute grid: 256 CU x 4 blocks/CU
#define BPB 4                    // max bins per block: ceil(3125/1024) = 4
#define ROW_W32 136              // u32 words per slab row: 128 + 8 pad
#define HVEC (NPOS * D / 4)      // 262,144 f32x4 groups of hidden to convert
#define NORM_TERM 11.512925f
#define LOG_K 4.605170186f       // log(100)

typedef float    f32x4 __attribute__((ext_vector_type(4)));
typedef unsigned u32x2 __attribute__((ext_vector_type(2)));
typedef unsigned u32x4 __attribute__((ext_vector_type(4)));
typedef __fp16   f16x2 __attribute__((ext_vector_type(2)));

__device__ __forceinline__ float softplus(float x) {
    return fmaxf(x, 0.f) + __logf(1.f + __expf(-fabsf(x)));
}

__device__ __forceinline__ unsigned pack_f16(float a, float b) {
#if __has_builtin(__builtin_amdgcn_cvt_pkrtz)
    f16x2 h = __builtin_amdgcn_cvt_pkrtz(a, b);
#else
    f16x2 h; h.x = (__fp16)a; h.y = (__fp16)b;
#endif
    union { f16x2 h; unsigned u; } c; c.h = h;
    return c.u;
}

#if __has_builtin(__builtin_amdgcn_fdot2)
#define DOT2(a, b, c) __builtin_amdgcn_fdot2((a), (b), (c), false)
#else
__device__ __forceinline__ float DOT2(f16x2 a, f16x2 b, float c) {
    return fmaf((float)a.x, (float)b.x, fmaf((float)a.y, (float)b.y, c));
}
#endif

union V4H { u32x4 u; f16x2 h[4]; };

// Pure-VALU 16-lane butterfly sum via DPP involutions (validated R7-R12).
template <int CTRL>
__device__ __forceinline__ float dpp_add(float x) {
    int y = __builtin_amdgcn_update_dpp(__float_as_int(x), __float_as_int(x),
                                        CTRL, 0xF, 0xF, false);
    return x + __int_as_float(y);
}
__device__ __forceinline__ float quarter_sum(float x) {
    x = dpp_add<0xB1>(x);    // quad_perm [1,0,3,2]
    x = dpp_add<0x4E>(x);    // quad_perm [2,3,0,1]
    x = dpp_add<0x141>(x);   // row_half_mirror
    x = dpp_add<0x140>(x);   // row_mirror
    return x;
}

// ---------- Pass 1: bin pairs (16-way sharded cursors) + hidden f32->f16 ----
// rec = (row%32)<<13 | pos<<1 | is_target
__global__ __launch_bounds__(256) void scatter_hconv_kernel(
    const int* __restrict__ target, const int* __restrict__ noise,
    const float* __restrict__ hidden,
    int* __restrict__ cursor, unsigned* __restrict__ buf,
    unsigned* __restrict__ htab32)
{
    const int p = blockIdx.x * 256 + threadIdx.x;   // grid exact

    int row, pos; unsigned flag;
    if (p < NPOS * K) { pos = p / K; row = noise[p]; flag = 0u; }
    else              { pos = p - NPOS * K; row = target[pos]; flag = 1u; }
    const int cell = (row >> 5) * NSHARD + (blockIdx.x & (NSHARD - 1));
    const int slot = atomicAdd(&cursor[cell], 1);
    if (slot < CAP_S)
        buf[(size_t)cell * CAP_S + slot] =
            ((unsigned)(row & (BIN_ROWS - 1)) << 13) | ((unsigned)pos << 1) | flag;

    if (p < HVEC) {                      // fused hidden f32->f16 (4 MB read)
        const f32x4 h4 = *((const f32x4*)hidden + p);
        u32x2 o;
        o.x = pack_f16(h4.x, h4.y);
        o.y = pack_f16(h4.z, h4.w);
        *(u32x2*)(htab32 + (size_t)p * 2) = o;
    }
}

// ---------- Pass 2: persistent 1024-block grid, bins strided by GRIDC -------
// Tail fix vs previous rev: 1042 blocks > 1024 resident slots meant a second
// scheduling round for 18 straggler blocks (~2x block time). Now each of 1024
// blocks owns bins {b, b+1024, b+2048 (, b+3072 if b<53)} with the same
// cross-bin register pipeline; worst-case imbalance drops to 4-vs-3 bins.
// Plus 1-deep in-loop hidden prefetch: while pair p computes, pair p+16's
// 512B f16 hidden row is in flight (global L2 latency overlapped).
// launch_bounds(256,4): 4 blocks/CU resident; VGPR cap 128 keeps the
// compiler from sinking the prefetch (R7's VGPR=36 defeat).
__global__ __launch_bounds__(256, 4) void compute_kernel(
    const unsigned* __restrict__ htab32, const float* __restrict__ weight,
    const float* __restrict__ bias, const float* __restrict__ noise_probs,
    const int* __restrict__ cursor, const unsigned* __restrict__ buf,
    float* __restrict__ out)
{
    __shared__ unsigned slab32[BIN_ROWS * ROW_W32];  // 17.4 KB f16 slab
    __shared__ float    sbias[BPB * BIN_ROWS];
    __shared__ float    slogp[BPB * BIN_ROWS];
    __shared__ unsigned plist[MAXTOT];
    __shared__ int      scnt[BPB * NSHARD];
    __shared__ int      pref[BPB][NSHARD + 1];
    __shared__ float    wsum[4];

    const int b0  = blockIdx.x;          // bins: b0 + j*GRIDC, j = 0..BPB-1
    const int tid = threadIdx.x;
    const int wave = tid >> 6;
    const int lane = tid & 63;
    const int q    = lane >> 4;
    const int ql   = lane & 15;

    // ---- prologue: cursors + prefixes for all (up to) BPB bins
    if (tid < BPB * NSHARD) {
        const int j = tid >> 4, s = tid & 15, bin = b0 + j * GRIDC;
        scnt[tid] = (bin < NBIN) ? min(cursor[bin * NSHARD + s], CAP_S) : 0;
    }
    __syncthreads();
    if (tid < BPB) {
        int s = 0;
        #pragma unroll
        for (int i = 0; i < NSHARD; ++i) { pref[tid][i] = s; s += scnt[tid * NSHARD + i]; }
        pref[tid][NSHARD] = s;
    }
    __syncthreads();

    // ---- stage bin 0 slab + plist, and bias/logp for all bins
    for (int r = wave; r < BIN_ROWS; r += 4) {
        const f32x4 w4 = __builtin_nontemporal_load(
            (const f32x4*)(weight + (size_t)(b0 * BIN_ROWS + r) * D + lane * 4));
        u32x2 o;
        o.x = pack_f16(w4.x, w4.y);
        o.y = pack_f16(w4.z, w4.w);
        *(u32x2*)(slab32 + r * ROW_W32 + lane * 2) = o;
    }
    if (tid < BPB * BIN_ROWS) {
        const int j = tid >> 5, r = tid & 31, bin = b0 + j * GRIDC;
        if (bin < NBIN) {
            sbias[tid] = bias[bin * BIN_ROWS + r];
            slogp[tid] = __logf(noise_probs[bin * BIN_ROWS + r]);
        }
    }
    {
        const int total0 = pref[0][NSHARD];
        for (int i = tid; i < total0; i += 256) {
            int s = 0;
            #pragma unroll
            for (int m = 1; m < NSHARD; ++m) s += (i >= pref[0][m]);
            plist[i] = buf[((size_t)(b0 * NSHARD + s)) * CAP_S + (i - pref[0][s])];
        }
    }
    __syncthreads();

    float loss = 0.f;
    for (int j = 0; j < BPB; ++j) {
        const int bin   = b0 + j * GRIDC;
        const int total = (bin < NBIN) ? pref[j][NSHARD] : 0;
        const int bin_n = bin + GRIDC;
        const bool hasnext = (j + 1 < BPB) && (bin_n < NBIN);

        // ---- issue next bin's slab loads into registers (in flight below)
        f32x4 wpre[8];
        if (hasnext) {
            const float* wsrc = weight + (size_t)bin_n * BIN_ROWS * D;
            #pragma unroll
            for (int i = 0; i < 8; ++i)
                wpre[i] = __builtin_nontemporal_load(
                    (const f32x4*)(wsrc + (size_t)(wave + 4 * i) * D + lane * 4));
        }
        // ---- prefetch next bin's plist records into registers
        unsigned pl_a = 0u, pl_b = 0u; int tot_n = 0;
        if (hasnext) {
            tot_n = pref[j + 1][NSHARD];
            if (tid < tot_n) {
                int s = 0;
                #pragma unroll
                for (int m = 1; m < NSHARD; ++m) s += (tid >= pref[j + 1][m]);
                pl_a = buf[((size_t)(bin_n * NSHARD + s)) * CAP_S + (tid - pref[j + 1][s])];
            }
            if (tid + 256 < tot_n) {
                int s = 0;
                #pragma unroll
                for (int m = 1; m < NSHARD; ++m) s += (tid + 256 >= pref[j + 1][m]);
                pl_b = buf[((size_t)(bin_n * NSHARD + s)) * CAP_S + (tid + 256 - pref[j + 1][s])];
            }
        }

        // ---- pair loop for bin j: 16 lanes/pair, 1-deep hidden prefetch
        {
            const int p0 = wave * 4 + q;
            unsigned rec_c = (p0 < total) ? plist[p0] : 0u;
            V4H H0c, H1c;
            {
                const u32x4* hp = (const u32x4*)(htab32
                    + (size_t)((rec_c >> 1) & (NPOS - 1)) * 128) + ql;
                H0c.u = hp[0];
                H1c.u = hp[16];
            }
            for (int base = wave * 4; base < total; base += 16) {
                const int p = base + q;
                // prefetch pair p+16's record + hidden row (in flight during dots)
                const int pn = p + 16;
                const unsigned rec_n = (pn < total) ? plist[pn] : 0u;
                const u32x4* hpn = (const u32x4*)(htab32
                    + (size_t)((rec_n >> 1) & (NPOS - 1)) * 128) + ql;
                V4H H0n, H1n;
                H0n.u = hpn[0];
                H1n.u = hpn[16];

                // compute pair p with pipelined hidden (H0c/H1c), slab at use
                const int rloc = (int)((rec_c >> 13) & (BIN_ROWS - 1));
                const unsigned* wr = slab32 + rloc * ROW_W32;
                V4H W0, W1;
                W0.u = *(const u32x4*)(wr + ql * 4);
                W1.u = *(const u32x4*)(wr + 64 + ql * 4);

                float a0 = 0.f, a1 = 0.f, a2 = 0.f, a3 = 0.f;
                a0 = DOT2(H0c.h[0], W0.h[0], a0);
                a1 = DOT2(H0c.h[1], W0.h[1], a1);
                a2 = DOT2(H0c.h[2], W0.h[2], a2);
                a3 = DOT2(H0c.h[3], W0.h[3], a3);
                a0 = DOT2(H1c.h[0], W1.h[0], a0);
                a1 = DOT2(H1c.h[1], W1.h[1], a1);
                a2 = DOT2(H1c.h[2], W1.h[2], a2);
                a3 = DOT2(H1c.h[3], W1.h[3], a3);

                const float r = quarter_sum((a0 + a1) + (a2 + a3));

                const float score = r + sbias[j * BIN_ROWS + rloc] - NORM_TERM;
                const float x = (rec_c & 1u) ? (LOG_K - score)
                                             : (score - slogp[j * BIN_ROWS + rloc] - LOG_K);
                if ((p < total) && ql == 0) loss += softplus(x);

                rec_c = rec_n;
                H0c = H0n;
                H1c = H1n;
            }
        }
        __syncthreads();   // all waves done reading slab/plist of bin j

        if (hasnext) {     // commit prefetched slab + plist for bin j+1
            #pragma unroll
            for (int i = 0; i < 8; ++i) {
                u32x2 o;
                o.x = pack_f16(wpre[i].x, wpre[i].y);
                o.y = pack_f16(wpre[i].z, wpre[i].w);
                *(u32x2*)(slab32 + (wave + 4 * i) * ROW_W32 + lane * 2) = o;
            }
            if (tid < tot_n)       plist[tid]       = pl_a;
            if (tid + 256 < tot_n) plist[tid + 256] = pl_b;
        }
        __syncthreads();
    }

    // fold quarters (loss lives on ql==0 lanes), then waves
    loss += __shfl_xor(loss, 16, 64);
    loss += __shfl_xor(loss, 32, 64);
    if (lane == 0) wsum[wave] = loss;
    __syncthreads();
    if (tid == 0)
        atomicAdd(out, (wsum[0] + wsum[1] + wsum[2] + wsum[3])
                       * (1.0f / (float)NPOS));
}

extern "C" void kernel_launch(void* const* d_in, const int* in_sizes, int n_in,
                              void* d_out, int out_size, void* d_ws, size_t ws_size,
                              hipStream_t stream) {
    const int*   target      = (const int*)d_in[0];
    const int*   noise       = (const int*)d_in[1];
    const float* hidden      = (const float*)d_in[2];
    const float* weight      = (const float*)d_in[3];
    const float* bias        = (const float*)d_in[4];
    const float* noise_probs = (const float*)d_in[5];
    float* out = (float*)d_out;

    // workspace: cursors (200 KB) | pair records (6.4 MB) | f16 hidden (2 MB)
    const size_t cursor_bytes = (size_t)NBIN * NSHARD * 4;
    const size_t buf_bytes    = (size_t)NBIN * NSHARD * CAP_S * 4;
    int*      cursor = (int*)d_ws;
    unsigned* buf    = (unsigned*)((char*)d_ws + cursor_bytes);
    unsigned* htab32 = (unsigned*)((char*)d_ws + cursor_bytes + buf_bytes);

    (void)hipMemsetAsync(cursor, 0, cursor_bytes, stream);
    (void)hipMemsetAsync(out, 0, sizeof(float), stream);   // d_out poisoned 0xAA

    scatter_hconv_kernel<<<NPAIR / 256, 256, 0, stream>>>(
        target, noise, hidden, cursor, buf, htab32);
    compute_kernel<<<GRIDC, 256, 0, stream>>>(
        htab32, weight, bias, noise_probs, cursor, buf, out);
}